// Round 6
// baseline (762.517 us; speedup 1.0000x reference)
//
#include <hip/hip_runtime.h>
#include <hip/hip_fp16.h>
#include <math.h>

#define NNODES 100000
#define BSH 9                 // 512 nodes per bucket
#define NBUCK 196             // ceil(100000/512)
#define CAP 18432             // padded bucket capacity (mean 16384, sigma ~127 -> 16 sigma)
#define EPB 16384             // edges per partition block
#define PBT 512

// ---------------- partition edges by dst bucket (padded regions, no global scan) ----------------
__global__ __launch_bounds__(512) void k_part(const int* __restrict__ src, const int* __restrict__ dst,
                                              int* __restrict__ bcur, unsigned int* __restrict__ part,
                                              int E) {
    __shared__ int h[512], lofs[512], lcur[512], gb[512];
    __shared__ unsigned int stage[EPB];
    int t = threadIdx.x;
    h[t] = 0;
    __syncthreads();
    int base = blockIdx.x * EPB;
    int n = min(EPB, E - base);
    for (int i = t; i < n; i += PBT) atomicAdd(&h[dst[base + i] >> BSH], 1);
    __syncthreads();
    lofs[t] = h[t];
    __syncthreads();
    for (int d = 1; d < 512; d <<= 1) {
        int v = (t >= d) ? lofs[t - d] : 0;
        __syncthreads();
        lofs[t] += v;
        __syncthreads();
    }
    int ex = lofs[t] - h[t];
    __syncthreads();
    lofs[t] = ex;
    lcur[t] = ex;
    gb[t] = 0;
    if (t < NBUCK && h[t]) gb[t] = atomicAdd(&bcur[t], h[t]);
    __syncthreads();
    for (int i = t; i < n; i += PBT) {
        int s = src[base + i], d = dst[base + i];
        int b = d >> BSH;
        int p = atomicAdd(&lcur[b], 1);
        stage[p] = (unsigned)s | ((unsigned)(d & 511) << 17);   // src 17b | dst-low 9b
    }
    __syncthreads();
    int wave = t >> 6, lane = t & 63;
    for (int b = wave; b < NBUCK; b += (PBT >> 6)) {
        int L = h[b], lo = lofs[b], g = gb[b];
        if (g + L > CAP) L = max(0, CAP - g);   // statistically impossible; guards corruption
        unsigned int* dp = part + (size_t)b * CAP + g;
        for (int j = lane; j < L; j += 64) dp[j] = stage[lo + j];
    }
}

// ---------------- per-bucket degree histogram -> dinv ----------------
__global__ __launch_bounds__(512) void k_deg(const unsigned int* __restrict__ part,
                                             const int* __restrict__ bcur, float* __restrict__ dinv) {
    __shared__ int hist[512];
    int t = threadIdx.x;
    hist[t] = 0;
    __syncthreads();
    int b = blockIdx.x;
    int ec = min(bcur[b], CAP);
    size_t base = (size_t)b * CAP;
    for (int i = t; i < ec; i += 512) atomicAdd(&hist[part[base + i] >> 17], 1);
    __syncthreads();
    int node = (b << BSH) + t;
    if (node < NNODES) dinv[node] = rsqrtf((float)(hist[t] + 1));
}

// ---------------- gemm1: h1s[n][j] = fp16( dinv[n] * sum_k x[n][k]*W1[k][j] ) ----------------
__global__ void k_gemm1(const float* __restrict__ x, const float* __restrict__ W1,
                        const float* __restrict__ dinv, __half* __restrict__ h1s, int n_nodes) {
    __shared__ float W[128 * 16];
    int t = threadIdx.x;
    for (int i = t; i < 128 * 16; i += 256) W[i] = W1[i];
    __syncthreads();
    int gid = blockIdx.x * 256 + t;
    int n = gid >> 4, j = gid & 15;
    if (n >= n_nodes) return;
    const float4* xr = (const float4*)(x + (size_t)n * 128);
    float acc = 0.f;
#pragma unroll
    for (int k4 = 0; k4 < 32; ++k4) {
        float4 xv = xr[k4];
        acc = fmaf(xv.x, W[(k4 * 4 + 0) * 16 + j], acc);
        acc = fmaf(xv.y, W[(k4 * 4 + 1) * 16 + j], acc);
        acc = fmaf(xv.z, W[(k4 * 4 + 2) * 16 + j], acc);
        acc = fmaf(xv.w, W[(k4 * 4 + 3) * 16 + j], acc);
    }
    h1s[(size_t)n * 16 + j] = __float2half(dinv[n] * acc);
}

// ---------------- bucket aggregation: LDS fp32 accumulate, fused epilogue ----------------
// LAYER 1: relu(dn*sum+b1) @ W2 * dn -> h3s fp16 (cols 10..15 zero)
// LAYER 2: dn*sum + b2 -> log_softmax -> out fp32
template <int LAYER>
__global__ __launch_bounds__(512) void k_aggb(const __half* __restrict__ h,
                                              const unsigned int* __restrict__ part,
                                              const int* __restrict__ bcur,
                                              const float* __restrict__ dinv,
                                              const float* __restrict__ bias,
                                              const float* __restrict__ W2,
                                              void* __restrict__ outp) {
    __shared__ float acc[512 * 17];
    __shared__ float sW2[160];
    __shared__ float sB[16];
    int t = threadIdx.x;
    if (LAYER == 1 && t < 160) sW2[t] = W2[t];
    if (t < ((LAYER == 1) ? 16 : 10)) sB[t] = bias[t];
    for (int i = t; i < 512 * 17; i += 512) acc[i] = 0.f;
    __syncthreads();

    int b = blockIdx.x;
    int ec = min(bcur[b], CAP);
    size_t base = (size_t)b * CAP;
    int fg = t & 3;        // feature group (4 halves)
    int eg = t >> 2;       // edge group: 128 groups of 4 lanes

    for (int i = eg; i < ec; i += 128) {
        unsigned v = part[base + i];
        int s = (int)(v & 0x1FFFFu);
        int dl = (int)(v >> 17);
        uint2 u = *(const uint2*)(h + (size_t)s * 16 + fg * 4);
        float2 f0 = __half22float2(*(__half2*)&u.x);
        float2 f1 = __half22float2(*(__half2*)&u.y);
        float* ap = &acc[dl * 17 + fg * 4];
        atomicAdd(ap + 0, f0.x);
        atomicAdd(ap + 1, f0.y);
        atomicAdd(ap + 2, f1.x);
        atomicAdd(ap + 3, f1.y);
    }
    __syncthreads();

    int node = (b << BSH) + t;
    if (node >= NNODES) return;
    float dn = dinv[node];
    float a[16];
    {   // acc row + self-loop term (h row of own node, already dinv-scaled)
        const uint2* sr = (const uint2*)(h + (size_t)node * 16);
#pragma unroll
        for (int q = 0; q < 4; ++q) {
            uint2 u = sr[q];
            float2 f0 = __half22float2(*(__half2*)&u.x);
            float2 f1 = __half22float2(*(__half2*)&u.y);
            a[q * 4 + 0] = acc[t * 17 + q * 4 + 0] + f0.x;
            a[q * 4 + 1] = acc[t * 17 + q * 4 + 1] + f0.y;
            a[q * 4 + 2] = acc[t * 17 + q * 4 + 2] + f1.x;
            a[q * 4 + 3] = acc[t * 17 + q * 4 + 3] + f1.y;
        }
    }

    if (LAYER == 1) {
        float hv[16];
#pragma unroll
        for (int j = 0; j < 16; ++j) hv[j] = fmaxf(fmaf(dn, a[j], sB[j]), 0.f);
        float vals[16];
#pragma unroll
        for (int jj = 0; jj < 16; ++jj) vals[jj] = 0.f;
#pragma unroll
        for (int jj = 0; jj < 10; ++jj) {
            float p = 0.f;
#pragma unroll
            for (int k = 0; k < 16; ++k) p = fmaf(hv[k], sW2[k * 10 + jj], p);
            vals[jj] = p * dn;
        }
        __half2 packed[8];
#pragma unroll
        for (int q = 0; q < 8; ++q) packed[q] = __floats2half2_rn(vals[2 * q], vals[2 * q + 1]);
        uint4* d4 = (uint4*)((__half*)outp + (size_t)node * 16);
        d4[0] = *(uint4*)&packed[0];
        d4[1] = *(uint4*)&packed[4];
    } else {
        float v[10], mx = -1e30f;
#pragma unroll
        for (int j = 0; j < 10; ++j) {
            v[j] = fmaf(dn, a[j], sB[j]);
            mx = fmaxf(mx, v[j]);
        }
        float se = 0.f;
#pragma unroll
        for (int j = 0; j < 10; ++j) se += __expf(v[j] - mx);
        float lse = mx + __logf(se);
        float* op = (float*)outp + (size_t)node * 10;
#pragma unroll
        for (int j = 0; j < 10; ++j) op[j] = v[j] - lse;
    }
}

// ---------------- launch ----------------

extern "C" void kernel_launch(void* const* d_in, const int* in_sizes, int n_in,
                              void* d_out, int out_size, void* d_ws, size_t ws_size,
                              hipStream_t stream) {
    const float* x  = (const float*)d_in[0];
    const int*   ei = (const int*)d_in[1];
    const float* W1 = (const float*)d_in[2];
    const float* b1 = (const float*)d_in[3];
    const float* W2 = (const float*)d_in[4];
    const float* b2 = (const float*)d_in[5];
    float* out = (float*)d_out;

    const int N = in_sizes[0] / 128;   // 100000
    const int E = in_sizes[1] / 2;     // 3200000
    const int* src = ei;
    const int* dst = ei + E;

    char* ws = (char*)d_ws;
    size_t o = 0;
    auto alloc = [&](size_t bytes) {
        size_t p = o;
        o = (o + bytes + 255) & ~(size_t)255;
        return p;
    };
    int*    bcur = (int*)(ws + alloc(512 * 4));
    float*  dinv = (float*)(ws + alloc((size_t)N * 4));
    unsigned int* part = (unsigned int*)(ws + alloc((size_t)NBUCK * CAP * 4));  // 14.5 MB
    __half* h1s  = (__half*)(ws + alloc((size_t)N * 16 * 2));
    __half* h3s  = (__half*)(ws + alloc((size_t)N * 16 * 2));

    hipMemsetAsync(bcur, 0, 512 * 4, stream);

    int gp = (E + EPB - 1) / EPB;   // 196
    k_part<<<gp, PBT, 0, stream>>>(src, dst, bcur, part, E);
    k_deg<<<NBUCK, 512, 0, stream>>>(part, bcur, dinv);

    int gg = (N * 16 + 255) / 256;
    k_gemm1<<<gg, 256, 0, stream>>>(x, W1, dinv, h1s, N);

    k_aggb<1><<<NBUCK, 512, 0, stream>>>(h1s, part, bcur, dinv, b1, W2, h3s);
    k_aggb<2><<<NBUCK, 512, 0, stream>>>(h3s, part, bcur, dinv, b2, W2, out);
}

// Round 7
// 165.318 us; speedup vs baseline: 4.6124x; 4.6124x over previous
//
#include <hip/hip_runtime.h>
#include <hip/hip_fp16.h>
#include <math.h>

#define NNODES 100000
#define BSH 8                 // 256 nodes per bucket
#define NBUCK 391             // ceil(100000/256)
#define CAP 10240             // padded bucket capacity (mean 8192, sigma ~90)
#define EPB 16384             // edges per partition block
#define PBT 512

__device__ inline __half2 shfl_xor_h2(__half2 v, int m) {
    union { __half2 h; int i; } u;
    u.h = v;
    u.i = __shfl_xor(u.i, m);
    return u.h;
}

// ---------------- partition edges by dst bucket (padded regions, no global scan) ----------------
__global__ __launch_bounds__(512) void k_part(const int* __restrict__ src, const int* __restrict__ dst,
                                              int* __restrict__ bcur, unsigned int* __restrict__ part,
                                              int E) {
    __shared__ int h[512], lofs[512], lcur[512], gb[512];
    __shared__ unsigned int stage[EPB];
    int t = threadIdx.x;
    h[t] = 0;
    __syncthreads();
    int base = blockIdx.x * EPB;
    int n = min(EPB, E - base);
    for (int i = t; i < n; i += PBT) atomicAdd(&h[dst[base + i] >> BSH], 1);
    __syncthreads();
    lofs[t] = h[t];
    __syncthreads();
    for (int d = 1; d < 512; d <<= 1) {
        int v = (t >= d) ? lofs[t - d] : 0;
        __syncthreads();
        lofs[t] += v;
        __syncthreads();
    }
    int ex = lofs[t] - h[t];
    __syncthreads();
    lofs[t] = ex;
    lcur[t] = ex;
    gb[t] = 0;
    if (t < NBUCK && h[t]) gb[t] = atomicAdd(&bcur[t], h[t]);
    __syncthreads();
    for (int i = t; i < n; i += PBT) {
        int s = src[base + i], d = dst[base + i];
        int b = d >> BSH;
        int p = atomicAdd(&lcur[b], 1);
        stage[p] = (unsigned)s | ((unsigned)(d & 255) << 17);
    }
    __syncthreads();
    int wave = t >> 6, lane = t & 63;
    for (int b = wave; b < NBUCK; b += (PBT >> 6)) {
        int L = h[b], lo = lofs[b], g = gb[b];
        if (g + L > CAP) L = max(0, CAP - g);   // statistically impossible; guards corruption
        unsigned int* dp = part + (size_t)b * CAP + g;
        for (int j = lane; j < L; j += 64) dp[j] = stage[lo + j];
    }
}

// ---------------- per-bucket CSR fill, in place (col aliases part) ----------------
__global__ __launch_bounds__(256) void k_bfill(unsigned int* __restrict__ part,
                                               const int* __restrict__ bcur,
                                               int* __restrict__ cnt, int* __restrict__ off,
                                               float* __restrict__ dinv) {
    __shared__ int lcnt[256], lscan[256], lcur[256];
    __shared__ unsigned int lraw[CAP];
    int t = threadIdx.x;
    int b = blockIdx.x;
    int ec = min(bcur[b], CAP);
    size_t base = (size_t)b * CAP;
    lcnt[t] = 0;
    __syncthreads();
    for (int i = t; i < ec; i += 256) {
        unsigned v = part[base + i];
        lraw[i] = v;
        atomicAdd(&lcnt[v >> 17], 1);
    }
    __syncthreads();
    lscan[t] = lcnt[t];
    __syncthreads();
    for (int d = 1; d < 256; d <<= 1) {
        int v = (t >= d) ? lscan[t - d] : 0;
        __syncthreads();
        lscan[t] += v;
        __syncthreads();
    }
    int ex = lscan[t] - lcnt[t];
    lcur[t] = ex;
    int node = (b << BSH) + t;
    if (node < NNODES) {
        off[node] = (int)base + ex;
        cnt[node] = lcnt[t];
        dinv[node] = rsqrtf((float)(lcnt[t] + 1));
    }
    __syncthreads();
    for (int i = t; i < ec; i += 256) {
        unsigned v = lraw[i];
        int p = atomicAdd(&lcur[v >> 17], 1);
        part[base + p] = v & 0x1FFFFu;
    }
}

// ---------------- gemm1: h1s[n][j] = fp16( dinv[n] * sum_k x[n][k]*W1[k][j] ) ----------------
__global__ void k_gemm1(const float* __restrict__ x, const float* __restrict__ W1,
                        const float* __restrict__ dinv, __half* __restrict__ h1s, int n_nodes) {
    __shared__ float W[128 * 16];
    int t = threadIdx.x;
    for (int i = t; i < 128 * 16; i += 256) W[i] = W1[i];
    __syncthreads();
    int gid = blockIdx.x * 256 + t;
    int n = gid >> 4, j = gid & 15;
    if (n >= n_nodes) return;
    const float4* xr = (const float4*)(x + (size_t)n * 128);
    float acc = 0.f;
#pragma unroll
    for (int k4 = 0; k4 < 32; ++k4) {
        float4 xv = xr[k4];
        acc = fmaf(xv.x, W[(k4 * 4 + 0) * 16 + j], acc);
        acc = fmaf(xv.y, W[(k4 * 4 + 1) * 16 + j], acc);
        acc = fmaf(xv.z, W[(k4 * 4 + 2) * 16 + j], acc);
        acc = fmaf(xv.w, W[(k4 * 4 + 3) * 16 + j], acc);
    }
    h1s[(size_t)n * 16 + j] = __float2half(dinv[n] * acc);
}

// ---------------- agg1: 4 nodes/wave. lane = ng*16 + sl*4 + fg ----------------
// sum h1s over neighbors -> relu(dn*sum+b1) -> @W2 -> *dn -> h3s (fp16, cols 10..15 = 0)
__global__ __launch_bounds__(256) void k_agg1(const __half* __restrict__ h1s, const unsigned int* __restrict__ col,
                                              const int* __restrict__ off, const int* __restrict__ cnt,
                                              const float* __restrict__ dinv, const float* __restrict__ b1,
                                              const float* __restrict__ W2, __half* __restrict__ h3s,
                                              int n_nodes) {
    __shared__ float sW2[16 * 17];    // [k][jj], jj zero-padded to 16, stride 17
    __shared__ float sB[16];
    int t = threadIdx.x;
    {
        int k = t >> 4, jj = t & 15;
        sW2[k * 17 + jj] = (jj < 10) ? W2[k * 10 + jj] : 0.f;
    }
    if (t < 16) sB[t] = b1[t];
    __syncthreads();
    int wid = (blockIdx.x * 256 + t) >> 4;       // one node per 16-lane group
    if (wid >= n_nodes) return;
    int lane = t & 63;
    int fg = lane & 3, sl = (lane >> 2) & 3;
    int deg = cnt[wid], o = off[wid];
    __half2 a0 = __floats2half2_rn(0.f, 0.f), a1 = a0;
    for (int e = sl; e < deg; e += 4) {
        int s = (int)col[o + e];
        uint2 u = *(const uint2*)(h1s + (size_t)s * 16 + fg * 4);
        a0 = __hadd2(a0, *(__half2*)&u.x);
        a1 = __hadd2(a1, *(__half2*)&u.y);
    }
    // reduce over sl (lane bits 2-3)
    a0 = __hadd2(a0, shfl_xor_h2(a0, 4));  a1 = __hadd2(a1, shfl_xor_h2(a1, 4));
    a0 = __hadd2(a0, shfl_xor_h2(a0, 8));  a1 = __hadd2(a1, shfl_xor_h2(a1, 8));
    {   // self-loop AFTER reduce (exactly once; uniform within node group)
        uint2 u = *(const uint2*)(h1s + (size_t)wid * 16 + fg * 4);
        a0 = __hadd2(a0, *(__half2*)&u.x);
        a1 = __hadd2(a1, *(__half2*)&u.y);
    }
    float2 f0 = __half22float2(a0), f1 = __half22float2(a1);
    float dn = dinv[wid];
    int k0 = fg * 4;
    float h0 = fmaxf(fmaf(dn, f0.x, sB[k0 + 0]), 0.f);
    float h1v = fmaxf(fmaf(dn, f0.y, sB[k0 + 1]), 0.f);
    float h2v = fmaxf(fmaf(dn, f1.x, sB[k0 + 2]), 0.f);
    float h3v = fmaxf(fmaf(dn, f1.y, sB[k0 + 3]), 0.f);
    // distributed matmul: lane computes cols jj = sl*4..sl*4+3 over its k-chunk [k0, k0+4)
    float p0, p1, p2, p3;
    {
        const float* w0 = &sW2[(k0 + 0) * 17 + sl * 4];
        const float* w1 = &sW2[(k0 + 1) * 17 + sl * 4];
        const float* w2 = &sW2[(k0 + 2) * 17 + sl * 4];
        const float* w3 = &sW2[(k0 + 3) * 17 + sl * 4];
        p0 = h0 * w0[0] + h1v * w1[0] + h2v * w2[0] + h3v * w3[0];
        p1 = h0 * w0[1] + h1v * w1[1] + h2v * w2[1] + h3v * w3[1];
        p2 = h0 * w0[2] + h1v * w1[2] + h2v * w2[2] + h3v * w3[2];
        p3 = h0 * w0[3] + h1v * w1[3] + h2v * w2[3] + h3v * w3[3];
    }
    // reduce over fg (lane bits 0-1)
    p0 += __shfl_xor(p0, 1); p0 += __shfl_xor(p0, 2);
    p1 += __shfl_xor(p1, 1); p1 += __shfl_xor(p1, 2);
    p2 += __shfl_xor(p2, 1); p2 += __shfl_xor(p2, 2);
    p3 += __shfl_xor(p3, 1); p3 += __shfl_xor(p3, 2);
    if (fg == 0) {
        __half2 w0 = __floats2half2_rn(p0 * dn, p1 * dn);
        __half2 w1 = __floats2half2_rn(p2 * dn, p3 * dn);
        union { __half2 h[2]; uint2 u; } pk;
        pk.h[0] = w0; pk.h[1] = w1;
        *(uint2*)(h3s + (size_t)wid * 16 + sl * 4) = pk.u;
    }
}

// ---------------- agg2: 4 nodes/wave. sum h3s -> *dn + b2 -> log_softmax -> out ----------------
__global__ __launch_bounds__(256) void k_agg2(const __half* __restrict__ h3s, const unsigned int* __restrict__ col,
                                              const int* __restrict__ off, const int* __restrict__ cnt,
                                              const float* __restrict__ dinv, const float* __restrict__ b2,
                                              float* __restrict__ out, int n_nodes) {
    int t = threadIdx.x;
    int wid = (blockIdx.x * 256 + t) >> 4;
    if (wid >= n_nodes) return;
    int lane = t & 63;
    int fg = lane & 3, sl = (lane >> 2) & 3;
    int deg = cnt[wid], o = off[wid];
    __half2 a0 = __floats2half2_rn(0.f, 0.f), a1 = a0;
    for (int e = sl; e < deg; e += 4) {
        int s = (int)col[o + e];
        uint2 u = *(const uint2*)(h3s + (size_t)s * 16 + fg * 4);
        a0 = __hadd2(a0, *(__half2*)&u.x);
        a1 = __hadd2(a1, *(__half2*)&u.y);
    }
    a0 = __hadd2(a0, shfl_xor_h2(a0, 4));  a1 = __hadd2(a1, shfl_xor_h2(a1, 4));
    a0 = __hadd2(a0, shfl_xor_h2(a0, 8));  a1 = __hadd2(a1, shfl_xor_h2(a1, 8));
    {   // self-loop AFTER reduce
        uint2 u = *(const uint2*)(h3s + (size_t)wid * 16 + fg * 4);
        a0 = __hadd2(a0, *(__half2*)&u.x);
        a1 = __hadd2(a1, *(__half2*)&u.y);
    }
    float2 f0 = __half22float2(a0), f1 = __half22float2(a1);
    float dn = dinv[wid];
    float a4[4] = {f0.x, f0.y, f1.x, f1.y};
    float v[4];
    float mx = -1e30f;
#pragma unroll
    for (int i = 0; i < 4; ++i) {
        int idx = fg * 4 + i;
        if (idx < 10) {
            v[i] = fmaf(dn, a4[i], b2[idx]);
            mx = fmaxf(mx, v[i]);
        } else v[i] = 0.f;
    }
    // reduce over fg (lane bits 0-1)
    mx = fmaxf(mx, __shfl_xor(mx, 1));
    mx = fmaxf(mx, __shfl_xor(mx, 2));
    float se = 0.f;
#pragma unroll
    for (int i = 0; i < 4; ++i) {
        int idx = fg * 4 + i;
        if (idx < 10) se += __expf(v[i] - mx);
    }
    se += __shfl_xor(se, 1);
    se += __shfl_xor(se, 2);
    float lse = mx + __logf(se);
    if (sl == 0) {
#pragma unroll
        for (int i = 0; i < 4; ++i) {
            int idx = fg * 4 + i;
            if (idx < 10) out[(size_t)wid * 10 + idx] = v[i] - lse;
        }
    }
}

// ---------------- launch ----------------

extern "C" void kernel_launch(void* const* d_in, const int* in_sizes, int n_in,
                              void* d_out, int out_size, void* d_ws, size_t ws_size,
                              hipStream_t stream) {
    const float* x  = (const float*)d_in[0];
    const int*   ei = (const int*)d_in[1];
    const float* W1 = (const float*)d_in[2];
    const float* b1 = (const float*)d_in[3];
    const float* W2 = (const float*)d_in[4];
    const float* b2 = (const float*)d_in[5];
    float* out = (float*)d_out;

    const int N = in_sizes[0] / 128;   // 100000
    const int E = in_sizes[1] / 2;     // 3200000
    const int* src = ei;
    const int* dst = ei + E;

    char* ws = (char*)d_ws;
    size_t o = 0;
    auto alloc = [&](size_t bytes) {
        size_t p = o;
        o = (o + bytes + 255) & ~(size_t)255;
        return p;
    };
    int*    bcur = (int*)(ws + alloc(512 * 4));
    int*    cnt  = (int*)(ws + alloc((size_t)N * 4));
    int*    off  = (int*)(ws + alloc((size_t)N * 4));
    float*  dinv = (float*)(ws + alloc((size_t)N * 4));
    unsigned int* part = (unsigned int*)(ws + alloc((size_t)NBUCK * CAP * 4));  // 16 MB
    __half* h1s  = (__half*)(ws + alloc((size_t)N * 16 * 2));
    __half* h3s  = (__half*)(ws + alloc((size_t)N * 16 * 2));

    hipMemsetAsync(bcur, 0, 512 * 4, stream);

    int gp = (E + EPB - 1) / EPB;   // 196
    k_part<<<gp, PBT, 0, stream>>>(src, dst, bcur, part, E);
    k_bfill<<<NBUCK, 256, 0, stream>>>(part, bcur, cnt, off, dinv);

    int gg = (N * 16 + 255) / 256;
    k_gemm1<<<gg, 256, 0, stream>>>(x, W1, dinv, h1s, N);

    int ga = (N * 16 + 255) / 256;   // 16 nodes per 256-thread block
    k_agg1<<<ga, 256, 0, stream>>>(h1s, part, off, cnt, dinv, b1, W2, h3s, N);
    k_agg2<<<ga, 256, 0, stream>>>(h3s, part, off, cnt, dinv, b2, out, N);
}